// Round 3
// baseline (93.201 us; speedup 1.0000x reference)
//
#include <hip/hip_runtime.h>
#include <hip/hip_bf16.h>
#include <stdint.h>

// CapsNet dynamic routing with J-axis of size 1 in softmax: cj == 1 identically,
// so b never feeds back and the op collapses to ONE GEMM + squash:
//   s[b][c] = sum_t In[b][t] * W2[t][c]      b<64, t<16384 (=i*8+k), c<512 (=j*16+l)
//   out[b][c] = squash over l (groups of 16)
// W2[t][c] address in W[I][J][K][L]: i*4096 + j*128 + k*16 + l.
//
// Correctness-first design (round-0 tr_b16 path was wrong): no LDS, no barriers.
// Fragments use ONLY the m91/m92-verified mfma_f32_16x16x32_bf16 layouts:
//   A[row][k]: row = lane&15, k = (lane>>4)*8 + e   (8 contiguous k per lane)
//   B[k][col]: col = lane&15, k = (lane>>4)*8 + e
//   D[row][col]: col = lane&15, row = (lane>>4)*4 + reg
// fp32 accuracy via hi/lo bf16 split: x ~= xh + xl, 3 MFMAs (hh, lh, hl).
// Kernel is memory-bound (24KB/step/block ~ 2400 cyc vs 120 cyc MFMA) so the
// strided scalar W loads are fine: every 64B segment is fully consumed.

using f32x4 = __attribute__((ext_vector_type(4))) float;
using s16x8 = __attribute__((ext_vector_type(8))) short;

__device__ __forceinline__ short f2bf(float x) {
    __hip_bfloat16 h = __float2bfloat16(x);   // round-to-nearest-even
    return *reinterpret_cast<short*>(&h);
}
__device__ __forceinline__ float bf2f(short s) {
    return __uint_as_float(((uint32_t)(uint16_t)s) << 16);
}

struct WBuf { float v[2][8];   };   // [ntile][e]  : W2[kb+q*8+e][c0+nt*16+cin]
struct IBuf { f32x4 v[4][2];   };   // [mtile][half]: In[mt*16+cin][kb+q*8 ..+7]

template<int KSPLITS>
__global__ __launch_bounds__(256)
void caps_gemm(const float* __restrict__ In, const float* __restrict__ W,
               float* __restrict__ ws)
{
    constexpr int KS    = 16384 / KSPLITS;  // t-extent per block
    constexpr int NSTEP = KS / 32;          // 32 t per MFMA K-step (always even)

    const int tid  = threadIdx.x;
    const int wv   = tid >> 6;
    const int lane = tid & 63;
    const int q    = lane >> 4;
    const int cin  = lane & 15;
    const int kb0  = blockIdx.x * KS;
    const int c0   = blockIdx.y * 128 + wv * 32;  // wave's first column (2 n-tiles)

    f32x4 acc[4][2] = {};  // [mtile][ntile], fp32 accumulation in MFMA

    auto load_step = [&](int s, WBuf& wb, IBuf& ib) {
        const int kb = kb0 + s * 32;
        const int i0 = (kb >> 3) + q;           // t0 = kb + q*8 is 8-aligned -> i row
        #pragma unroll
        for (int nt = 0; nt < 2; ++nt) {
            const int c = c0 + nt * 16 + cin;
            const float* wp = W + (size_t)i0 * 4096 + (c >> 4) * 128 + (c & 15);
            #pragma unroll
            for (int e = 0; e < 8; ++e) wb.v[nt][e] = wp[e * 16];  // k = e
        }
        #pragma unroll
        for (int mt = 0; mt < 4; ++mt) {
            const float* ip = In + (size_t)(mt * 16 + cin) * 16384 + kb + q * 8;
            ib.v[mt][0] = *(const f32x4*)(ip);
            ib.v[mt][1] = *(const f32x4*)(ip + 4);
        }
    };

    auto compute = [&](const WBuf& wb, const IBuf& ib) {
        s16x8 Ah[4], Al[4], Bh[2], Bl[2];
        #pragma unroll
        for (int mt = 0; mt < 4; ++mt)
            #pragma unroll
            for (int e = 0; e < 8; ++e) {
                float x = ib.v[mt][e >> 2][e & 3];
                short h = f2bf(x);
                Ah[mt][e] = h;
                Al[mt][e] = f2bf(x - bf2f(h));
            }
        #pragma unroll
        for (int nt = 0; nt < 2; ++nt)
            #pragma unroll
            for (int e = 0; e < 8; ++e) {
                float x = wb.v[nt][e];
                short h = f2bf(x);
                Bh[nt][e] = h;
                Bl[nt][e] = f2bf(x - bf2f(h));
            }
        #pragma unroll
        for (int mt = 0; mt < 4; ++mt)
            #pragma unroll
            for (int nt = 0; nt < 2; ++nt) {
                acc[mt][nt] = __builtin_amdgcn_mfma_f32_16x16x32_bf16(Ah[mt], Bh[nt], acc[mt][nt], 0, 0, 0);
                acc[mt][nt] = __builtin_amdgcn_mfma_f32_16x16x32_bf16(Al[mt], Bh[nt], acc[mt][nt], 0, 0, 0);
                acc[mt][nt] = __builtin_amdgcn_mfma_f32_16x16x32_bf16(Ah[mt], Bl[nt], acc[mt][nt], 0, 0, 0);
            }
    };

    // register-only double buffer; phases are statically named (no runtime idx)
    WBuf wA, wB;
    IBuf iA, iB;
    load_step(0, wA, iA);
    #pragma unroll 1
    for (int ss = 0; ss < NSTEP; ss += 2) {
        load_step(ss + 1, wB, iB);              // NSTEP even -> always valid
        compute(wA, iA);
        if (ss + 2 < NSTEP) load_step(ss + 2, wA, iA);
        compute(wB, iB);
    }

    // D tile (mt,nt): row b = mt*16 + q*4 + r, col c = c0 + nt*16 + cin
    float* wsb = ws + (size_t)blockIdx.x * 32768;   // [b][c] slab per k-split
    #pragma unroll
    for (int mt = 0; mt < 4; ++mt)
        #pragma unroll
        for (int nt = 0; nt < 2; ++nt) {
            const int c = c0 + nt * 16 + cin;
            #pragma unroll
            for (int r = 0; r < 4; ++r)
                wsb[(mt * 16 + q * 4 + r) * 512 + c] = acc[mt][nt][r];
        }
}

__global__ __launch_bounds__(256)
void caps_finish(const float* __restrict__ ws, float* __restrict__ out, int nk)
{
    const int o = blockIdx.x * 256 + threadIdx.x;   // o = b*512 + j*16 + l
    float s = 0.0f;
    #pragma unroll 8
    for (int ks = 0; ks < nk; ++ks) s += ws[(size_t)ks * 32768 + o];
    float s2 = s * s;                                // sum s^2 over l (16 lanes)
    s2 += __shfl_xor(s2, 1);
    s2 += __shfl_xor(s2, 2);
    s2 += __shfl_xor(s2, 4);
    s2 += __shfl_xor(s2, 8);
    const float scale = s2 / (1.0f + s2);
    out[o] = s * scale / sqrtf(s2 + 1e-7f);
}

extern "C" void kernel_launch(void* const* d_in, const int* in_sizes, int n_in,
                              void* d_out, int out_size, void* d_ws, size_t ws_size,
                              hipStream_t stream)
{
    (void)in_sizes; (void)n_in; (void)out_size;
    const float* In = (const float*)d_in[0];   // [64][2048][8]
    const float* W  = (const float*)d_in[1];   // [2048][32][8][16]
    float* out = (float*)d_out;                // 32768 floats
    float* ws  = (float*)d_ws;

    const size_t slab = 32768u * sizeof(float);     // one k-split partial: 128 KiB
    if (ws_size >= 128 * slab) {
        // 512 blocks -> 2 blocks/CU -> 2 waves/SIMD: better latency hiding
        caps_gemm<128><<<dim3(128, 4), dim3(256), 0, stream>>>(In, W, ws);
        caps_finish<<<dim3(128), dim3(256), 0, stream>>>(ws, out, 128);
    } else if (ws_size >= 64 * slab) {
        caps_gemm<64><<<dim3(64, 4), dim3(256), 0, stream>>>(In, W, ws);
        caps_finish<<<dim3(128), dim3(256), 0, stream>>>(ws, out, 64);
    } else if (ws_size >= 8 * slab) {
        caps_gemm<8><<<dim3(8, 4), dim3(256), 0, stream>>>(In, W, ws);
        caps_finish<<<dim3(128), dim3(256), 0, stream>>>(ws, out, 8);
    } else {
        // ultimate fallback: d_out itself holds the single partial (in-place safe:
        // each finish thread reads only its own element before writing it)
        caps_gemm<1><<<dim3(1, 4), dim3(256), 0, stream>>>(In, W, out);
        caps_finish<<<dim3(128), dim3(256), 0, stream>>>(out, out, 1);
    }
}